// Round 2
// 309.350 us; speedup vs baseline: 1.0055x; 1.0055x over previous
//
#include <hip/hip_runtime.h>
#include <hip/hip_bf16.h>

#define Bb 2
#define Ss 2048
#define Hh 2048
#define NH 16
#define NKV 4
#define HD 128
#define NREP (NH / NKV)
#define Mrows (Bb * Ss)          // 4096
#define NQKV (NH*HD + 2*NKV*HD)  // 3072

using short8 = __attribute__((ext_vector_type(8))) short;
using f32x4  = __attribute__((ext_vector_type(4))) float;

__device__ __forceinline__ unsigned short f2b(float f) {
  union { float f; unsigned u; } v; v.f = f;
  return (unsigned short)((v.u + 0x7fffu + ((v.u >> 16) & 1u)) >> 16);
}

__device__ __forceinline__ void gload16(const void* g, void* l) {
  __builtin_amdgcn_global_load_lds(
      (const __attribute__((address_space(1))) unsigned int*)g,
      (__attribute__((address_space(3))) unsigned int*)l, 16, 0, 0);
}

// ---------------- prep: x->bf16  |  wq|wk|wv transpose (rotary-permuted)  |  wo transpose ----------------
__global__ void prep(const float* __restrict__ x, unsigned short* __restrict__ xb,
                     const float* __restrict__ wq, const float* __restrict__ wk,
                     const float* __restrict__ wv, unsigned short* __restrict__ wqkvt,
                     const float* __restrict__ wo, unsigned short* __restrict__ wot) {
  __shared__ float tile[32][33];
  const int bid = blockIdx.x;
  const int t = threadIdx.x;
  if (bid < 8192) {
    int i = (bid * 256 + t) * 4;
    float4 f = *(const float4*)(x + i);
    ushort4 o;
    o.x = f2b(f.x); o.y = f2b(f.y); o.z = f2b(f.z); o.w = f2b(f.w);
    *(ushort4*)(xb + i) = o;
    return;
  }
  const int tx = t & 31, ty = t >> 5;
  if (bid < 8192 + 6144) {
    int idx = bid - 8192;
    int n0 = (idx % 96) * 32, k0 = (idx / 96) * 32;
    const float* src; int base, C;
    if (n0 < Hh)            { src = wq; base = 0;        C = NH * HD; }
    else if (n0 < Hh + 512) { src = wk; base = Hh;       C = NKV * HD; }
    else                    { src = wv; base = Hh + 512; C = NKV * HD; }
    int ng = n0 + tx;
    int cmg = ng;
    if (ng < Hh + 512) {                    // q or k: rotary permutation
      int j = ng & 127;
      cmg = (ng & ~127) + ((j >> 5) << 4) + (j & 15) + ((j >> 4) & 1) * 64;
    }
    int col = cmg - base;
    #pragma unroll
    for (int i = ty; i < 32; i += 8)
      tile[i][tx] = src[(long)(k0 + i) * C + col];
    __syncthreads();
    #pragma unroll
    for (int i = ty; i < 32; i += 8)
      wqkvt[(long)(n0 + i) * Hh + k0 + tx] = f2b(tile[tx][i]);
  } else {
    int idx = bid - 8192 - 6144;
    int n0 = (idx % 64) * 32, k0 = (idx / 64) * 32;
    #pragma unroll
    for (int i = ty; i < 32; i += 8)
      tile[i][tx] = wo[(long)(k0 + i) * Hh + n0 + tx];
    __syncthreads();
    #pragma unroll
    for (int i = ty; i < 32; i += 8)
      wot[(long)(n0 + i) * Hh + k0 + tx] = f2b(tile[tx][i]);
  }
}

// ---------------- QKV GEMM v5: 256x256 8-phase schedule (T2+T3+T4+T5), fused RoPE / V-transpose ----------------
// grid 192: nt = idx>>4 (0..11: 0-7 q, 8-9 k, 10-11 v), mt = idx&15.
// 512 thr = 8 waves (2M x 4N), per-wave C = 128x64, BK=64, 2 K-tile LDS dbuf (128 KiB).
// Per K-tile: 4 phases, quadrant snake (0,0)->(0,1)->(1,1)->(1,0); prefetch of tile t+1
// front-loaded in phases 0-1 (>=2-phase lead); one vmcnt drain per tile at the boundary.
// Granule swizzle: slot s of row r holds source granule s^(r&7) (pre-swizzled global src).
__global__ __launch_bounds__(512, 2) void gemm_qkv(const unsigned short* __restrict__ A,
                                                   const unsigned short* __restrict__ Bt,
                                                   const float* __restrict__ cosT,
                                                   const float* __restrict__ sinT,
                                                   unsigned short* __restrict__ qt,
                                                   unsigned short* __restrict__ kt,
                                                   unsigned short* __restrict__ vt) {
  __shared__ unsigned short As[2][256 * 64];
  __shared__ unsigned short Bs[2][256 * 64];
  const int t = threadIdx.x;
  const int lane = t & 63, wid = t >> 6;
  const int quad = lane >> 4, l16 = lane & 15;
  const int nt = blockIdx.x >> 4, mt = blockIdx.x & 15;
  const int n0 = nt * 256, m0 = mt * 256;
  const int wm = (wid >> 2) * 128, wn = (wid & 3) * 64;
  const bool isv = nt >= 10;
  const int Kk = Hh;

  // staging: thread t loads row wid*8+(lane>>3) (+i*64), source granule (lane&7)^(lane>>3)
  const int sg = (lane & 7) ^ (lane >> 3);
  const int srow = wid * 8 + (lane >> 3);
  const unsigned short* Ag = A  + (long)(m0 + srow) * Kk + sg * 8;
  const unsigned short* Bg = Bt + (long)(n0 + srow) * Kk + sg * 8;

  f32x4 acc[8][4] = {};
  short8 aH[4][2], bH[2][2];

#define STAGE_A(buf, k0) { _Pragma("unroll") for (int i = 0; i < 4; i++) \
    gload16(Ag + (long)i * 64 * Kk + (k0), &As[buf][wid * 512 + i * 4096]); }
#define STAGE_B(buf, k0) { _Pragma("unroll") for (int i = 0; i < 4; i++) \
    gload16(Bg + (long)i * 64 * Kk + (k0), &Bs[buf][wid * 512 + i * 4096]); }
#define LDA(buf, mh) { _Pragma("unroll") for (int qq = 0; qq < 4; qq++) \
    _Pragma("unroll") for (int ks = 0; ks < 2; ks++) \
      aH[qq][ks] = *(const short8*)(&As[buf][(wm + (mh) * 64 + qq * 16 + l16) * 64 + \
                                             (((ks * 4 + quad) ^ (l16 & 7)) * 8)]); }
#define LDB(buf, nh) { _Pragma("unroll") for (int qq = 0; qq < 2; qq++) \
    _Pragma("unroll") for (int ks = 0; ks < 2; ks++) \
      bH[qq][ks] = *(const short8*)(&Bs[buf][(wn + (nh) * 32 + qq * 16 + l16) * 64 + \
                                             (((ks * 4 + quad) ^ (l16 & 7)) * 8)]); }
#define MM(mh, nh) { __builtin_amdgcn_s_setprio(1); \
    if (!isv) { \
      _Pragma("unroll") for (int qq = 0; qq < 4; qq++) \
      _Pragma("unroll") for (int n2 = 0; n2 < 2; n2++) \
      _Pragma("unroll") for (int ks = 0; ks < 2; ks++) \
        acc[(mh)*4+qq][(nh)*2+n2] = __builtin_amdgcn_mfma_f32_16x16x32_bf16( \
            aH[qq][ks], bH[n2][ks], acc[(mh)*4+qq][(nh)*2+n2], 0, 0, 0); \
    } else { \
      _Pragma("unroll") for (int qq = 0; qq < 4; qq++) \
      _Pragma("unroll") for (int n2 = 0; n2 < 2; n2++) \
      _Pragma("unroll") for (int ks = 0; ks < 2; ks++) \
        acc[(mh)*4+qq][(nh)*2+n2] = __builtin_amdgcn_mfma_f32_16x16x32_bf16( \
            bH[n2][ks], aH[qq][ks], acc[(mh)*4+qq][(nh)*2+n2], 0, 0, 0); \
    } __builtin_amdgcn_s_setprio(0); }
#define BAR() __builtin_amdgcn_s_barrier()
#define LGK0() asm volatile("s_waitcnt lgkmcnt(0)" ::: "memory")

  // prologue: stage tile 0 into buf 0
  STAGE_A(0, 0); STAGE_B(0, 0);
  asm volatile("s_waitcnt vmcnt(0)" ::: "memory");
  BAR();

  for (int kt2 = 0; kt2 < Kk / 64; ++kt2) {
    const int cur = kt2 & 1, nxt = cur ^ 1;
    const long k0n = (long)(kt2 + 1) * 64;
    const bool pf = (kt2 + 1 < Kk / 64);
    // phase 0: quad (0,0); prefetch A of tile t+1
    LDA(cur, 0); LDB(cur, 0);
    if (pf) STAGE_A(nxt, k0n);
    BAR(); LGK0(); MM(0, 0); BAR();
    // phase 1: quad (0,1); prefetch B of tile t+1
    LDB(cur, 1);
    if (pf) STAGE_B(nxt, k0n);
    BAR(); LGK0(); MM(0, 1); BAR();
    // phase 2: quad (1,1)
    LDA(cur, 1);
    BAR(); LGK0(); MM(1, 1); BAR();
    // phase 3: quad (1,0); tile-boundary drain (loads had >=2 phases of lead)
    LDB(cur, 0);
    BAR(); LGK0(); MM(1, 0);
    asm volatile("s_waitcnt vmcnt(0)" ::: "memory");
    BAR();
  }

#undef STAGE_A
#undef STAGE_B
#undef LDA
#undef LDB
#undef MM
#undef BAR
#undef LGK0

  if (!isv) {
    // RoPE epilogue: pair (NI, NI+1), within-head permuted base = (cb&127)
    #pragma unroll
    for (int MI = 0; MI < 8; MI++)
      #pragma unroll
      for (int r = 0; r < 4; r++) {
        int srw = m0 + wm + MI * 16 + quad * 4 + r;
        int bb = srw >> 11, s = srw & (Ss - 1);
        const float* cr = cosT + (long)s * HD;
        const float* sr = sinT + (long)s * HD;
        #pragma unroll
        for (int NI = 0; NI < 4; NI += 2) {
          int cb = n0 + wn + NI * 16;
          bool isq = cb < NH * HD;
          int hh = isq ? (cb >> 7) : ((cb - NH * HD) >> 7);
          unsigned short* dst = isq ? qt + (((long)bb * NH + hh) * Ss + s) * HD
                                    : kt + (((long)bb * NKV + hh) * Ss + s) * HD;
          int d = (((cb & 127) >> 5) << 4) + l16;
          float cc = cr[d], sn = sr[d];
          float x0 = acc[MI][NI][r], x1 = acc[MI][NI + 1][r];
          dst[d]      = f2b(x0 * cc - x1 * sn);
          dst[d + 64] = f2b(x1 * cc + x0 * sn);
        }
      }
  } else {
    // V epilogue (swapped operands -> transposed acc): coalesced vt[d][s] store
    #pragma unroll
    for (int MI = 0; MI < 8; MI++) {
      int srw = m0 + wm + MI * 16 + l16;
      int bb = srw >> 11, s = srw & (Ss - 1);
      #pragma unroll
      for (int NI = 0; NI < 4; NI++)
        #pragma unroll
        for (int r = 0; r < 4; r++) {
          int vcol = n0 - (NH * HD + NKV * HD) + wn + NI * 16 + quad * 4 + r;
          int kvh = vcol >> 7, d = vcol & 127;
          vt[(((long)bb * NKV + kvh) * HD + d) * Ss + s] = f2b(acc[MI][NI][r]);
        }
    }
  }
}

// ---------------- GEMM2 (unchanged proven version): C(MxN fp32) = A * Bt^T ----------------
__global__ __launch_bounds__(256) void gemm_bt(const unsigned short* __restrict__ A,
                                               const unsigned short* __restrict__ Bt,
                                               float* __restrict__ Cv,
                                               int Mm, int Nn, int Kk) {
  __shared__ unsigned short As[128 * 64];
  __shared__ unsigned short Bs[128 * 64];
  const int t = threadIdx.x;
  const int lane = t & 63, wave = t >> 6;
  const int quad = lane >> 4, l16 = lane & 15;
  const int n0 = (blockIdx.x >> 5) * 128, m0 = (blockIdx.x & 31) * 128;
  const int wm = (wave >> 1) * 64, wn = (wave & 1) * 64;

  f32x4 acc[4][4] = {};

  const int srow = t >> 3;
  const int sgr  = (t & 7) ^ (srow & 7);
  const unsigned short* Ag = A  + (long)(m0 + srow) * Kk + sgr * 8;
  const unsigned short* Bg = Bt + (long)(n0 + srow) * Kk + sgr * 8;
  unsigned short* lA = As + (wave * 64) * 8;
  unsigned short* lB = Bs + (wave * 64) * 8;

  for (int k0 = 0; k0 < Kk; k0 += 64) {
    #pragma unroll
    for (int i = 0; i < 4; i++)
      gload16(Ag + (long)i * 32 * Kk + k0, lA + i * 256 * 8);
    #pragma unroll
    for (int i = 0; i < 4; i++)
      gload16(Bg + (long)i * 32 * Kk + k0, lB + i * 256 * 8);
    __syncthreads();

    #pragma unroll
    for (int sub = 0; sub < 2; sub++) {
      short8 af[4], bf[4];
      #pragma unroll
      for (int i = 0; i < 4; i++)
        af[i] = *(const short8*)(As + (wm + i * 16 + l16) * 64 + (((sub * 4 + quad) ^ (l16 & 7)) * 8));
      #pragma unroll
      for (int i = 0; i < 4; i++)
        bf[i] = *(const short8*)(Bs + (wn + i * 16 + l16) * 64 + (((sub * 4 + quad) ^ (l16 & 7)) * 8));

      #pragma unroll
      for (int mi = 0; mi < 4; mi++)
        #pragma unroll
        for (int ni = 0; ni < 4; ni++)
          acc[mi][ni] = __builtin_amdgcn_mfma_f32_16x16x32_bf16(af[mi], bf[ni], acc[mi][ni], 0, 0, 0);
    }
    __syncthreads();
  }

  #pragma unroll
  for (int mi = 0; mi < 4; mi++)
    #pragma unroll
    for (int ni = 0; ni < 4; ni++)
      #pragma unroll
      for (int r = 0; r < 4; r++) {
        long row = m0 + wm + mi * 16 + quad * 4 + r;
        long col = n0 + wn + ni * 16 + l16;
        Cv[row * Nn + col] = acc[mi][ni][r];
      }
}

// ---------------- flash attention v6 (proven R9): fixed-shift softmax, dbuf K+V, XCD mapping ----------------
__global__ __launch_bounds__(256, 2) void flash_attn(const unsigned short* __restrict__ qt,
                                                     const unsigned short* __restrict__ kt,
                                                     const unsigned short* __restrict__ vt,
                                                     unsigned short* __restrict__ out) {
  __shared__ unsigned short Ks[2][64 * 128];
  __shared__ unsigned short Vs[2][128 * 64];

  const int w = threadIdx.x >> 6, lane = threadIdx.x & 63;
  const int quad = lane >> 4, l16 = lane & 15;
  const int r8 = lane >> 3, c8 = lane & 7;
  const int idx = blockIdx.x;
  const int xcd = idx & 7;
  const int b = xcd >> 2, kvh = xcd & 3;
  const int rest = idx >> 3;               // 0..63
  const int k16 = rest >> 2;               // 0..15
  const int qblk = (k16 < 8) ? (15 - k16) : (k16 - 8);
  const int h = kvh * NREP + (rest & 3);
  const int q0w = qblk * 128 + w * 32;

  const unsigned short* Qb = qt + ((long)b * NH + h) * Ss * HD;
  const unsigned short* Kb = kt + ((long)b * NKV + kvh) * Ss * HD;
  const unsigned short* Vb = vt + ((long)b * NKV + kvh) * HD * Ss;
  const int nch = (qblk + 1) * 2;

  #pragma unroll
  for (int i = 0; i < 4; i++) {
    int rho = i * 16 + w * 4 + quad;
    int key = (rho & 32) + ((rho >> 2) & 3) * 8 + ((rho >> 4) & 1) * 4 + (rho & 3);
    int sg = l16 ^ (w * 4 + quad);
    gload16(Kb + (long)key * HD + sg * 8, &Ks[0][(i * 256 + w * 64) * 8]);
  }
  #pragma unroll
  for (int i = 0; i < 4; i++) {
    int dv = i * 32 + w * 8 + r8;
    int sg = c8 ^ r8;
    gload16(Vb + (long)dv * Ss + sg * 8, &Vs[0][(i * 256 + w * 64) * 8]);
  }

  short8 qf[2][4];
  #pragma unroll
  for (int qi = 0; qi < 2; qi++)
    #pragma unroll
    for (int kc = 0; kc < 4; kc++)
      qf[qi][kc] = *(const short8*)(Qb + (long)(q0w + qi * 16 + l16) * HD + kc * 32 + quad * 8);

  f32x4 accO[2][8] = {};
  float l_i[2];
  l_i[0] = l_i[1] = 0.f;
  const float cscale = 1.4426950408889634f * 0.08838834764831845f; // log2e / sqrt(128)

  for (int c = 0; c < nch; ++c) {
    const unsigned short* Ksb = Ks[c & 1];
    const unsigned short* Vsb = Vs[c & 1];

    if (c + 1 < nch) {
      const int k0 = (c + 1) * 64;
      unsigned short* Kd = Ks[(c + 1) & 1];
      unsigned short* Vd = Vs[(c + 1) & 1];
      #pragma unroll
      for (int i = 0; i < 4; i++) {
        int rho = i * 16 + w * 4 + quad;
        int key = (rho & 32) + ((rho >> 2) & 3) * 8 + ((rho >> 4) & 1) * 4 + (rho & 3);
        int sg = l16 ^ (w * 4 + quad);
        gload16(Kb + (long)(k0 + key) * HD + sg * 8, Kd + (i * 256 + w * 64) * 8);
      }
      #pragma unroll
      for (int i = 0; i < 4; i++) {
        int dv = i * 32 + w * 8 + r8;
        int sg = c8 ^ r8;
        gload16(Vb + (long)dv * Ss + k0 + sg * 8, Vd + (i * 256 + w * 64) * 8);
      }
      asm volatile("s_waitcnt vmcnt(8)" ::: "memory");
    } else {
      asm volatile("s_waitcnt vmcnt(0)" ::: "memory");
    }
    asm volatile("s_barrier" ::: "memory");

    if (c * 64 < q0w + 32) {
      f32x4 sc[2][4] = {};
      #pragma unroll
      for (int T = 0; T < 4; T++)
        #pragma unroll
        for (int kc = 0; kc < 4; kc++) {
          short8 kf = *(const short8*)(Ksb + ((16 * T + l16) * 16 + ((kc * 4 + quad) ^ l16)) * 8);
          #pragma unroll
          for (int qi = 0; qi < 2; qi++)
            sc[qi][T] = __builtin_amdgcn_mfma_f32_16x16x32_bf16(kf, qf[qi][kc], sc[qi][T], 0, 0, 0);
        }

      if ((c + 1) * 64 - 1 > q0w) {
        #pragma unroll
        for (int qi = 0; qi < 2; qi++) {
          int qq = q0w + qi * 16 + l16;
          #pragma unroll
          for (int T = 0; T < 4; T++)
            #pragma unroll
            for (int r = 0; r < 4; r++) {
              int ka = c * 64 + (T >> 1) * 32 + quad * 8 + (T & 1) * 4 + r;
              if (ka > qq) sc[qi][T][r] = -__builtin_inff();
            }
        }
      }

      short8 pf[2][2];
      #pragma unroll
      for (int qi = 0; qi < 2; qi++) {
        float p[4][4], rs = 0.f;
        #pragma unroll
        for (int T = 0; T < 4; T++)
          #pragma unroll
          for (int r = 0; r < 4; r++) {
            p[T][r] = __builtin_amdgcn_exp2f(sc[qi][T][r] * cscale);
            rs += p[T][r];
          }
        rs += __shfl_xor(rs, 16);
        rs += __shfl_xor(rs, 32);
        l_i[qi] += rs;

        #pragma unroll
        for (int c2 = 0; c2 < 2; c2++) {
          short8 f;
          f[0] = (short)f2b(p[2 * c2][0]);     f[1] = (short)f2b(p[2 * c2][1]);
          f[2] = (short)f2b(p[2 * c2][2]);     f[3] = (short)f2b(p[2 * c2][3]);
          f[4] = (short)f2b(p[2 * c2 + 1][0]); f[5] = (short)f2b(p[2 * c2 + 1][1]);
          f[6] = (short)f2b(p[2 * c2 + 1][2]); f[7] = (short)f2b(p[2 * c2 + 1][3]);
          pf[qi][c2] = f;
        }
      }

      #pragma unroll
      for (int c2 = 0; c2 < 2; c2++)
        #pragma unroll
        for (int Dt = 0; Dt < 8; Dt++) {
          short8 vf = *(const short8*)(Vsb + ((16 * Dt + l16) * 8 + ((4 * c2 + quad) ^ (l16 & 7))) * 8);
          #pragma unroll
          for (int qi = 0; qi < 2; qi++)
            accO[qi][Dt] = __builtin_amdgcn_mfma_f32_16x16x32_bf16(vf, pf[qi][c2], accO[qi][Dt], 0, 0, 0);
        }
    }

    asm volatile("s_waitcnt lgkmcnt(0)" ::: "memory");
    asm volatile("s_barrier" ::: "memory");
  }

  #pragma unroll
  for (int qi = 0; qi < 2; qi++) {
    float inv = 1.f / l_i[qi];
    long orow = (long)b * Ss + q0w + qi * 16 + l16;
    #pragma unroll
    for (int Dt = 0; Dt < 8; Dt++) {
      ushort4 o;
      o.x = f2b(accO[qi][Dt][0] * inv);
      o.y = f2b(accO[qi][Dt][1] * inv);
      o.z = f2b(accO[qi][Dt][2] * inv);
      o.w = f2b(accO[qi][Dt][3] * inv);
      *(ushort4*)(out + orow * (NH * HD) + h * HD + Dt * 16 + quad * 4) = o;
    }
  }
}

extern "C" void kernel_launch(void* const* d_in, const int* in_sizes, int n_in,
                              void* d_out, int out_size, void* d_ws, size_t ws_size,
                              hipStream_t stream) {
  const float* x    = (const float*)d_in[0];
  const float* cosT = (const float*)d_in[1];
  const float* sinT = (const float*)d_in[2];
  const float* wq   = (const float*)d_in[3];
  const float* wk   = (const float*)d_in[4];
  const float* wv   = (const float*)d_in[5];
  const float* wo   = (const float*)d_in[6];
  float* out = (float*)d_out;

  char* ws = (char*)d_ws;
  unsigned short* xb    = (unsigned short*)(ws);                       // 16 MiB
  unsigned short* wqkvt = (unsigned short*)(ws + (16l << 20));         // 12 MiB
  unsigned short* wot   = (unsigned short*)(ws + (28l << 20));         // 8 MiB
  unsigned short* qt    = (unsigned short*)(ws + (36l << 20));         // 16 MiB
  unsigned short* kt    = (unsigned short*)(ws + (52l << 20));         // 4 MiB
  unsigned short* vt    = (unsigned short*)(ws + (56l << 20));         // 4 MiB
  unsigned short* attno = xb;   // alias: xb dead after gemm_qkv

  prep<<<8192 + 6144 + 4096, 256, 0, stream>>>(x, xb, wq, wk, wv, wqkvt, wo, wot);

  // 256x256 8-phase QKV GEMM: 12 n-tiles x 16 m-tiles, 512 threads
  gemm_qkv<<<(NQKV / 256) * (Mrows / 256), 512, 0, stream>>>(xb, wqkvt, cosT, sinT, qt, kt, vt);

  flash_attn<<<(Ss / 128) * NH * Bb, 256, 0, stream>>>(qt, kt, vt, attno);

  gemm_bt<<<(Hh / 128) * (Mrows / 128), 256, 0, stream>>>(attno, wot, out, Mrows, Hh, Hh);
}